// Round 4
// baseline (106.787 us; speedup 1.0000x reference)
//
#include <hip/hip_runtime.h>

// Problem constants (from reference)
constexpr int S = 8192;    // source codes
constexpr int G = 1024;    // groups
constexpr int T = 4096;    // time segments (t0 sorted ascending)
constexpr int E = 16384;   // events
constexpr int CH = 16;     // output rows per slab/block
constexpr int NC = T / CH; // 256 slabs -> 1 block per CU in k_main
constexpr int MAXPTS = 1024; // bucket capacity (expected peak ~240/slab)

// ws layout:
//   [0, 1MB)            bdiff : float[NC][G]  slab-level diff -> base prefix
//   [1MB, 1MB+4KB)      pcnt  : int[NC] bucket cursors (padded)
//   [1MB+4KB, +2MB)     pts   : int2[NC][MAXPTS] packed (g<<4|row, w)
constexpr size_t OFF_PCNT = 1u << 20;
constexpr size_t OFF_PTS  = (1u << 20) + 4096;

// K0: zero bdiff + pcnt (harness poisons ws with 0xAA).
__global__ __launch_bounds__(256) void k_zero(float4* __restrict__ p, int n4) {
    int i = blockIdx.x * blockDim.x + threadIdx.x;
    if (i < n4) p[i] = make_float4(0.f, 0.f, 0.f, 0.f);
}

// K1: per-event prep. t0 staged in LDS; two binary searches give the active
// row range [lo, hi). Emit +w point at row lo (bucket sl) and -w point at
// row hi (bucket sh, if hi<T), plus slab-level diff into bdiff for the base
// prefix: base[s][g] must include +w iff sl<s and -w iff sh<s.
__global__ __launch_bounds__(256) void k_prep(
        const int* __restrict__ index, const float* __restrict__ rate,
        const float* __restrict__ start, const float* __restrict__ endt,
        const float* __restrict__ t0, const int* __restrict__ gid,
        const float* __restrict__ wts,
        float* __restrict__ bdiff, int* __restrict__ pcnt, int2* __restrict__ pts) {
    __shared__ float st0[T];                 // 16 KB
    int tid = threadIdx.x;
    for (int i = tid; i < T; i += 256) st0[i] = t0[i];
    __syncthreads();

    int e = blockIdx.x * 256 + tid;
    float s = start[e], en = endt[e];
    int lo = 0, hi = T;                      // lower_bound(t0, s)
    while (lo < hi) { int m = (lo + hi) >> 1; if (st0[m] < s) lo = m + 1; else hi = m; }
    int lo2 = lo, hi2 = T;                   // lower_bound(t0, en), en >= s
    while (lo2 < hi2) { int m = (lo2 + hi2) >> 1; if (st0[m] < en) lo2 = m + 1; else hi2 = m; }
    if (lo >= lo2) return;                   // never active

    int ix = index[e];
    float w = rate[e] * wts[ix];
    int g = gid[ix];
    int sl = lo >> 4, sh = lo2 >> 4;

    atomicAdd(bdiff + sl * G + g, w);
    int p1 = atomicAdd(pcnt + sl, 1);
    if (p1 < MAXPTS) { int2 r; r.x = (g << 4) | (lo & 15); r.y = __float_as_int(w); pts[sl * MAXPTS + p1] = r; }
    if (lo2 < T) {
        atomicAdd(bdiff + sh * G + g, -w);
        int p2 = atomicAdd(pcnt + sh, 1);
        if (p2 < MAXPTS) { int2 r; r.x = (g << 4) | (lo2 & 15); r.y = __float_as_int(-w); pts[sh * MAXPTS + p2] = r; }
    }
}

// K2: in-place exclusive column prefix over slabs: bdiff[s][g] <- sum_{x<s}.
// One column per thread, coalesced across threads; same-thread RMW in place.
__global__ __launch_bounds__(128) void k_base(float* __restrict__ bdiff) {
    int g = blockIdx.x * 128 + threadIdx.x;  // 8 blocks -> 1024 columns
    float r = 0.f;
    for (int s = 0; s < NC; ++s) {
        float v = bdiff[s * G + g];
        bdiff[s * G + g] = r;
        r += v;
    }
}

// K3: one block per slab. Zero 64KB LDS diff, scatter this slab's ~190
// bucket points (LDS atomics), seed each column with its base, scan CH rows
// (one column per thread, conflict-free), coalesced float4 slab write.
__global__ __launch_bounds__(1024) void k_main(
        const float* __restrict__ bdiff, const int* __restrict__ pcnt,
        const int2* __restrict__ pts, float* __restrict__ out) {
    __shared__ float diff[CH * G];           // 64 KB
    int tid = threadIdx.x;
    int s = blockIdx.x;

    float4* d4 = (float4*)diff;
    #pragma unroll
    for (int i = tid; i < CH * G / 4; i += 1024)
        d4[i] = make_float4(0.f, 0.f, 0.f, 0.f);
    __syncthreads();

    int n = min(pcnt[s], MAXPTS);
    for (int i = tid; i < n; i += 1024) {
        int2 p = pts[s * MAXPTS + i];
        atomicAdd(diff + (p.x & 15) * G + (p.x >> 4), __int_as_float(p.y));
    }
    __syncthreads();

    float r = bdiff[s * G + tid];            // base for column tid
    #pragma unroll
    for (int t = 0; t < CH; ++t) {
        r += diff[t * G + tid];
        diff[t * G + tid] = r;
    }
    __syncthreads();

    float4* o4 = (float4*)(out + (size_t)s * CH * G);
    #pragma unroll
    for (int i = tid; i < CH * G / 4; i += 1024)
        o4[i] = d4[i];
}

extern "C" void kernel_launch(void* const* d_in, const int* in_sizes, int n_in,
                              void* d_out, int out_size, void* d_ws, size_t ws_size,
                              hipStream_t stream) {
    const int*   index = (const int*)  d_in[0];
    const float* rate  = (const float*)d_in[1];
    const float* start = (const float*)d_in[2];
    const float* endt  = (const float*)d_in[3];
    const float* t0    = (const float*)d_in[4];
    const int*   gid   = (const int*)  d_in[5];
    const float* wts   = (const float*)d_in[6];
    float* out   = (float*)d_out;
    char*  ws    = (char*)d_ws;
    float* bdiff = (float*)ws;
    int*   pcnt  = (int*)(ws + OFF_PCNT);
    int2*  pts   = (int2*)(ws + OFF_PTS);

    int n4 = (int)((OFF_PTS) / 16);          // zero bdiff + pcnt pad (1MB+4KB)
    k_zero<<<(n4 + 255) / 256, 256, 0, stream>>>((float4*)ws, n4);
    k_prep<<<E / 256, 256, 0, stream>>>(index, rate, start, endt, t0, gid, wts,
                                        bdiff, pcnt, pts);
    k_base<<<G / 128, 128, 0, stream>>>(bdiff);
    k_main<<<NC, 1024, 0, stream>>>(bdiff, pcnt, pts, out);
}

// Round 5
// 106.673 us; speedup vs baseline: 1.0011x; 1.0011x over previous
//
#include <hip/hip_runtime.h>

// Problem constants (from reference)
constexpr int S = 8192;    // source codes
constexpr int G = 1024;    // groups
constexpr int T = 4096;    // time segments (t0 sorted ascending)
constexpr int E = 16384;   // events
constexpr int CH = 16;     // output rows per slab/block
constexpr int NC = T / CH; // 256 slabs -> 1 block per CU in k_main
constexpr int NCH = 16;    // chunks of slabs for the 2-level base prefix
constexpr int MAXPTS = 1024; // bucket capacity (expected peak ~250/slab)

// ws layout:
//   [0, 1MB)          bdiff : float[NC][G]   raw slab-level diffs
//   [1MB, 1MB+4KB)    pcnt  : int[NC] bucket cursors (padded to 4KB)
//   [1MB+4KB, +2MB)   pts   : int2[NC][MAXPTS] packed (g<<4|row, w)
//   [3MB+4KB, +64KB)  cs    : float[NCH][G]  chunk sums of bdiff
constexpr size_t OFF_PCNT = 1u << 20;
constexpr size_t OFF_PTS  = OFF_PCNT + 4096;
constexpr size_t OFF_CS   = OFF_PTS + (size_t)NC * MAXPTS * 8;

// K0: zero bdiff + pcnt (harness poisons ws with 0xAA).
__global__ __launch_bounds__(256) void k_zero(float4* __restrict__ p, int n4) {
    int i = blockIdx.x * blockDim.x + threadIdx.x;
    if (i < n4) p[i] = make_float4(0.f, 0.f, 0.f, 0.f);
}

// K1: per-event prep. t0 staged in LDS; two binary searches give the active
// row range [lo, hi). Emit +w point at row lo (bucket lo>>4) and -w point at
// row hi (bucket hi>>4, if hi<T), plus the same +/-w into the slab-level
// diff bdiff for the base prefix.
__global__ __launch_bounds__(256) void k_prep(
        const int* __restrict__ index, const float* __restrict__ rate,
        const float* __restrict__ start, const float* __restrict__ endt,
        const float* __restrict__ t0, const int* __restrict__ gid,
        const float* __restrict__ wts,
        float* __restrict__ bdiff, int* __restrict__ pcnt, int2* __restrict__ pts) {
    __shared__ float st0[T];                 // 16 KB
    int tid = threadIdx.x;
    for (int i = tid; i < T; i += 256) st0[i] = t0[i];
    __syncthreads();

    int e = blockIdx.x * 256 + tid;
    float s = start[e], en = endt[e];
    int lo = 0, hi = T;                      // lower_bound(t0, s)
    while (lo < hi) { int m = (lo + hi) >> 1; if (st0[m] < s) lo = m + 1; else hi = m; }
    int lo2 = lo, hi2 = T;                   // lower_bound(t0, en), en >= s
    while (lo2 < hi2) { int m = (lo2 + hi2) >> 1; if (st0[m] < en) lo2 = m + 1; else hi2 = m; }
    if (lo >= lo2) return;                   // never active

    int ix = index[e];
    float w = rate[e] * wts[ix];
    int g = gid[ix];
    int sl = lo >> 4, sh = lo2 >> 4;

    atomicAdd(bdiff + sl * G + g, w);
    int p1 = atomicAdd(pcnt + sl, 1);
    if (p1 < MAXPTS) { int2 r; r.x = (g << 4) | (lo & 15); r.y = __float_as_int(w); pts[sl * MAXPTS + p1] = r; }
    if (lo2 < T) {
        atomicAdd(bdiff + sh * G + g, -w);
        int p2 = atomicAdd(pcnt + sh, 1);
        if (p2 < MAXPTS) { int2 r; r.x = (g << 4) | (lo2 & 15); r.y = __float_as_int(-w); pts[sh * MAXPTS + p2] = r; }
    }
}

// K2: chunk sums cs[c][g] = sum of bdiff over the 16 slabs of chunk c.
// 64 blocks x 256 threads = 16K threads; 16 coalesced loads + 1 store each.
__global__ __launch_bounds__(256) void k_csum(const float* __restrict__ bdiff,
                                              float* __restrict__ cs) {
    int b = blockIdx.x;                      // 64 blocks: c = b>>2, g-quarter = b&3
    int c = b >> 2;
    int g = ((b & 3) << 8) | threadIdx.x;
    const float* p = bdiff + (size_t)(c * 16) * G + g;
    float a = 0.f;
    #pragma unroll
    for (int x = 0; x < 16; ++x) a += p[(size_t)x * G];
    cs[c * G + g] = a;
}

// K3: one 1024-thread block per slab. Zero 64KB LDS diff, scatter this
// slab's ~190 bucket points (LDS atomics), compute the column base inline
// from cs (<=15 loads) + bdiff (<=15 loads) — all coalesced, L2-resident —
// then scan CH rows (one column per thread, conflict-free) and write the
// slab with coalesced float4 stores.
__global__ __launch_bounds__(1024) void k_main(
        const float* __restrict__ bdiff, const float* __restrict__ cs,
        const int* __restrict__ pcnt, const int2* __restrict__ pts,
        float* __restrict__ out) {
    __shared__ float diff[CH * G];           // 64 KB
    int tid = threadIdx.x;
    int s = blockIdx.x;

    float4* d4 = (float4*)diff;
    #pragma unroll
    for (int i = tid; i < CH * G / 4; i += 1024)
        d4[i] = make_float4(0.f, 0.f, 0.f, 0.f);
    __syncthreads();

    int n = min(pcnt[s], MAXPTS);
    for (int i = tid; i < n; i += 1024) {
        int2 p = pts[s * MAXPTS + i];
        atomicAdd(diff + (p.x & 15) * G + (p.x >> 4), __int_as_float(p.y));
    }

    // Base for column tid: full chunks before s, then partial chunk.
    int c = s >> 4;
    float r = 0.f;
    for (int cc = 0; cc < c; ++cc) r += cs[cc * G + tid];
    for (int x = (c << 4); x < s; ++x) r += bdiff[(size_t)x * G + tid];
    __syncthreads();

    #pragma unroll
    for (int t = 0; t < CH; ++t) {
        r += diff[t * G + tid];
        diff[t * G + tid] = r;
    }
    __syncthreads();

    float4* o4 = (float4*)(out + (size_t)s * CH * G);
    #pragma unroll
    for (int i = tid; i < CH * G / 4; i += 1024)
        o4[i] = d4[i];
}

extern "C" void kernel_launch(void* const* d_in, const int* in_sizes, int n_in,
                              void* d_out, int out_size, void* d_ws, size_t ws_size,
                              hipStream_t stream) {
    const int*   index = (const int*)  d_in[0];
    const float* rate  = (const float*)d_in[1];
    const float* start = (const float*)d_in[2];
    const float* endt  = (const float*)d_in[3];
    const float* t0    = (const float*)d_in[4];
    const int*   gid   = (const int*)  d_in[5];
    const float* wts   = (const float*)d_in[6];
    float* out   = (float*)d_out;
    char*  ws    = (char*)d_ws;
    float* bdiff = (float*)ws;
    int*   pcnt  = (int*)(ws + OFF_PCNT);
    int2*  pts   = (int2*)(ws + OFF_PTS);
    float* cs    = (float*)(ws + OFF_CS);

    int n4 = (int)(OFF_PTS / 16);            // zero bdiff + pcnt (1MB + 4KB)
    k_zero<<<(n4 + 255) / 256, 256, 0, stream>>>((float4*)ws, n4);
    k_prep<<<E / 256, 256, 0, stream>>>(index, rate, start, endt, t0, gid, wts,
                                        bdiff, pcnt, pts);
    k_csum<<<64, 256, 0, stream>>>(bdiff, cs);
    k_main<<<NC, 1024, 0, stream>>>(bdiff, cs, pcnt, pts, out);
}

// Round 6
// 88.076 us; speedup vs baseline: 1.2124x; 1.2111x over previous
//
#include <hip/hip_runtime.h>

// Problem constants (from reference)
constexpr int S = 8192;    // source codes
constexpr int G = 1024;    // groups
constexpr int T = 4096;    // time segments (t0 sorted ascending)
constexpr int E = 16384;   // events
constexpr int CH = 16;     // output rows per slab/block
constexpr int NC = T / CH; // 256 slabs -> 1 block per CU in k_main
constexpr int BT = 1024;   // k_main threads (16 waves -> 4/SIMD w/ 64KB LDS)

// Record packing (8 B/event, halves the all-blocks record broadcast):
//   x = lo(12) | (hi-1)(12)<<12 | g.low8<<24      lo in [0,4095], hi in [1,4096]
//   y = float_bits(w) with low 2 bits = g.high2   (|rel err| <= 4e-7, harmless)
// Never-active events encode as lo=0, hi=1, g=0, w=0 -> adds 0.0, uniform loop.

// K1: per-event prep. t0 staged in LDS; two binary searches give the active
// row range [lo, hi); emit one packed 8-byte record.
__global__ __launch_bounds__(256) void k_prep(
        const int* __restrict__ index, const float* __restrict__ rate,
        const float* __restrict__ start, const float* __restrict__ endt,
        const float* __restrict__ t0, const int* __restrict__ gid,
        const float* __restrict__ wts, int2* __restrict__ rec) {
    __shared__ float st0[T];                 // 16 KB
    int tid = threadIdx.x;
    for (int i = tid; i < T; i += 256) st0[i] = t0[i];
    __syncthreads();

    int e = blockIdx.x * 256 + tid;          // grid covers E exactly
    float s = start[e], en = endt[e];
    int lo = 0, hi = T;                      // lower_bound(t0, s)
    while (lo < hi) { int m = (lo + hi) >> 1; if (st0[m] < s) lo = m + 1; else hi = m; }
    int lo2 = lo, hi2 = T;                   // lower_bound(t0, en), en >= s
    while (lo2 < hi2) { int m = (lo2 + hi2) >> 1; if (st0[m] < en) lo2 = m + 1; else hi2 = m; }

    int2 r;
    if (lo < lo2) {
        int ix = index[e];
        float w = rate[e] * wts[ix];
        int g = gid[ix];
        r.x = lo | ((lo2 - 1) << 12) | ((g & 0xFF) << 24);
        r.y = (__float_as_int(w) & ~3) | (g >> 8);
    } else {
        r.x = 0;                             // lo=0, hi=1, g=0
        r.y = 0;                             // w = +0.0f
    }
    rec[e] = r;
}

// K2: one 1024-thread block per CH-row slab. Slab diff in LDS; stream all E
// packed records (coalesced 8B loads, L2-resident broadcast: 32 MB total),
// clamp each interval to the slab, <=2 LDS atomics on overlap; then a
// conflict-free column scan (one g-column per thread) and a coalesced
// float4 slab write. Every output element is overwritten -> no zeroing pass.
__global__ __launch_bounds__(BT) void k_main(const int2* __restrict__ rec,
                                             float* __restrict__ out) {
    __shared__ float diff[CH * G];           // 64 KB
    int tid = threadIdx.x;
    int tb = blockIdx.x * CH;                // first t-row of this slab

    float4* d4 = (float4*)diff;
    #pragma unroll
    for (int i = tid; i < CH * G / 4; i += BT)
        d4[i] = make_float4(0.f, 0.f, 0.f, 0.f);
    __syncthreads();

    #pragma unroll 4
    for (int e = tid; e < E; e += BT) {
        int2 p = rec[e];
        int lo = (p.x & 0xFFF) - tb;
        int hi = ((p.x >> 12) & 0xFFF) + 1 - tb;
        int l = max(lo, 0), h = min(hi, CH);
        if (l < h) {
            int g = ((p.x >> 24) & 0xFF) | ((p.y & 3) << 8);
            float w = __int_as_float(p.y & ~3);
            atomicAdd(diff + l * G + g, w);
            if (h < CH) atomicAdd(diff + h * G + g, -w);
        }
    }
    __syncthreads();

    // Column prefix-sum: thread tid owns column g=tid; consecutive lanes hit
    // consecutive banks -> conflict-free.
    float r = 0.f;
    #pragma unroll
    for (int t = 0; t < CH; ++t) {
        r += diff[t * G + tid];
        diff[t * G + tid] = r;
    }
    __syncthreads();

    float4* o4 = (float4*)(out + (size_t)tb * G);
    #pragma unroll
    for (int i = tid; i < CH * G / 4; i += BT)
        o4[i] = d4[i];
}

extern "C" void kernel_launch(void* const* d_in, const int* in_sizes, int n_in,
                              void* d_out, int out_size, void* d_ws, size_t ws_size,
                              hipStream_t stream) {
    const int*   index = (const int*)  d_in[0];
    const float* rate  = (const float*)d_in[1];
    const float* start = (const float*)d_in[2];
    const float* endt  = (const float*)d_in[3];
    const float* t0    = (const float*)d_in[4];
    const int*   gid   = (const int*)  d_in[5];
    const float* wts   = (const float*)d_in[6];
    float* out = (float*)d_out;
    int2* rec = (int2*)d_ws;                 // E * 8 B = 128 KB

    k_prep<<<E / 256, 256, 0, stream>>>(index, rate, start, endt, t0, gid, wts, rec);
    k_main<<<NC, BT, 0, stream>>>(rec, out);
}